// Round 11
// baseline (357.038 us; speedup 1.0000x reference)
//
#include <hip/hip_runtime.h>
#include <hip/hip_bf16.h>

#define NROWS 32768
#define DDIM  4096
#define ODIM  256
#define EPSV  1e-5f

#define CHUNKS 128
#define RPC    256      // rows per chunk (CHUNKS*RPC == NROWS)

#define BM 64           // rows per block (2 waves of 32 rows x 2 col-halves)
#define BK 64
#define NKT (DDIM / BK)   // 64 K-steps

typedef __attribute__((ext_vector_type(4))) float          f32x4;
typedef __attribute__((ext_vector_type(8))) __bf16         bf16x8;
typedef __attribute__((ext_vector_type(8))) unsigned short u16x8;
typedef __attribute__((ext_vector_type(4))) unsigned short u16x4;

static __device__ __forceinline__ unsigned short f2bf(float f) {
  return __builtin_bit_cast(unsigned short, __float2bfloat16(f));
}
static __device__ __forceinline__ float bf2f(unsigned short u) {
  return __builtin_bit_cast(float, ((unsigned)u) << 16);
}

// ---------------- k1: per-chunk column partial sums (R1-proven) ----------------
__global__ __launch_bounds__(256) void k1_stats(const float* __restrict__ x,
                                                float* __restrict__ psum,
                                                float* __restrict__ psq) {
  const int col = blockIdx.x * 1024 + threadIdx.x * 4;
  const float* p = x + (size_t)blockIdx.y * RPC * DDIM + col;
  f32x4 s = {0.f, 0.f, 0.f, 0.f};
  f32x4 q = {0.f, 0.f, 0.f, 0.f};
#pragma unroll 8
  for (int r = 0; r < RPC; ++r) {
    f32x4 v = *(const f32x4*)p;
    p += DDIM;
    s += v;
    q += v * v;
  }
  *(f32x4*)(psum + (size_t)blockIdx.y * DDIM + col) = s;
  *(f32x4*)(psq  + (size_t)blockIdx.y * DDIM + col) = q;
}

// ------- k2: finalize -> bf16 AC table ([group of 8 cols][a0..7|c0..7]) + Wb ---
__global__ __launch_bounds__(256) void k2_finalize_wconv(
    const float* __restrict__ psum, const float* __restrict__ psq,
    const float* __restrict__ gamma, const float* __restrict__ beta,
    const float* __restrict__ Wf,
    unsigned short* __restrict__ AC, unsigned short* __restrict__ Wb) {
  if (blockIdx.x < 64) {
    __shared__ float ss[4][64];
    __shared__ float sq[4][64];
    const int lane = threadIdx.x & 63;
    const int g    = threadIdx.x >> 6;          // 0..3
    const int d    = blockIdx.x * 64 + lane;
    float s = 0.f, qq = 0.f;
    for (int c = g * 32; c < (g + 1) * 32; ++c) {
      s  += psum[(size_t)c * DDIM + d];
      qq += psq [(size_t)c * DDIM + d];
    }
    ss[g][lane] = s;
    sq[g][lane] = qq;
    __syncthreads();
    if (g == 0) {
      s  = ss[0][lane] + ss[1][lane] + ss[2][lane] + ss[3][lane];
      qq = sq[0][lane] + sq[1][lane] + sq[2][lane] + sq[3][lane];
      const float inv = 1.0f / (float)NROWS;
      const float mean = s * inv;
      const float var  = fmaxf(qq * inv - mean * mean, 0.f);
      const float a = gamma[d] * rsqrtf(var + EPSV);
      AC[(d >> 3) * 16 + (d & 7)]     = f2bf(a);
      AC[(d >> 3) * 16 + 8 + (d & 7)] = f2bf(beta[d] - mean * a);
    }
  } else {
    const size_t i = ((size_t)(blockIdx.x - 64) * 256 + threadIdx.x) * 4;
    f32x4 v = *(const f32x4*)(Wf + i);
    u16x4 o;
    o[0] = f2bf(v[0]); o[1] = f2bf(v[1]); o[2] = f2bf(v[2]); o[3] = f2bf(v[3]);
    *(u16x4*)(Wb + i) = o;
  }
}

// ---------------- k3: BARRIER-FREE fused normalize+relu+bf16 GEMM --------------
// 4 independent waves/block; wave = 32 rows x 128 cols (accA/accB[8]).
// A + AC -> registers (asm loads); B -> private per-wave 16KB LDS ring
// (half per kk) via own-wave global_load_lds. Wave-local counted vmcnt
// only; ZERO __syncthreads. 512 blocks = 2 blocks/CU, ~2 waves/SIMD.
__global__ __launch_bounds__(256, 2) void k3_bn_gemm(
    const float* __restrict__ x,
    const unsigned short* __restrict__ Wb,
    const unsigned short* __restrict__ AC,
    const float* __restrict__ bias,
    float* __restrict__ out) {
  __shared__ unsigned short BLDS[4 * 8192];   // 4 waves x 16 KB (2 x 8 KB halves)

  const int tid = threadIdx.x;
  const int l   = tid & 63;
  const int w   = tid >> 6;     // 0..3
  const int wr  = w >> 1;       // 0..1 row-half
  const int wc  = w & 1;        // 0..1 col-half
  const int lr  = l & 15;
  const int lc  = l >> 4;       // 0..3
  const size_t bm0 = (size_t)blockIdx.x * BM;

  // --- A stream: lane covers rows (bm0+wr*32+lr) and +16, cols lc*8 (+kk*32) --
  const float* xm0 = x + (bm0 + wr * 32 + lr) * (size_t)DDIM + lc * 8;
  const float* xm1 = xm0 + (size_t)16 * DDIM;
  // --- AC stream: group g = t*8 + kk*4 + lc; ushort addr = g*16 ---
  const unsigned short* acp = AC + lc * 16;

  // --- B gl_lds source: unit u = batch*64 + l -> col = batch*16 + (l>>2),
  //     sub = l&3; src = Wb[(wc*128+col)*4096 + t*64 + kk*32 + sub*8] ---
  const unsigned short* bptr =
      Wb + (size_t)(wc * 128 + (l >> 2)) * DDIM + (l & 3) * 8;

  // --- LDS: wave base; read addr lane part; col-major 16B units ---
  unsigned short* ldsw = &BLDS[w * 8192];            // ushort units
  const unsigned dsb =
      (unsigned)(uintptr_t)&BLDS[w * 8192] + (unsigned)(lr * 64 + lc * 16);

  const f32x4 zero = {0.f, 0.f, 0.f, 0.f};
  f32x4 accA[8], accB[8];
#pragma unroll
  for (int j = 0; j < 8; ++j) { accA[j] = zero; accB[j] = zero; }

  f32x4 S0, S1, S2, S3, S4, S5, S6, S7;   // x raw (m0k0,m0k1,m1k0,m1k1)
  u16x8 T0, T1, T2, T3;                   // AC raw (k0 a|c, k1 a|c)
  u16x8 pA00, pA10, pA01, pA11;           // pk set A: m0k0,m1k0,m0k1,m1k1
  u16x8 pB00, pB10, pB01, pB11;           // pk set B

#define SB __builtin_amdgcn_sched_barrier(0)

// 12 loads: x (8) + AC (4); advances pointers one K-step
#define ISSUE_AX()                                                             \
  asm volatile("global_load_dwordx4 %0, %1, off"            : "=v"(S0) : "v"(xm0)); \
  asm volatile("global_load_dwordx4 %0, %1, off offset:16"  : "=v"(S1) : "v"(xm0)); \
  asm volatile("global_load_dwordx4 %0, %1, off offset:128" : "=v"(S2) : "v"(xm0)); \
  asm volatile("global_load_dwordx4 %0, %1, off offset:144" : "=v"(S3) : "v"(xm0)); \
  asm volatile("global_load_dwordx4 %0, %1, off"            : "=v"(S4) : "v"(xm1)); \
  asm volatile("global_load_dwordx4 %0, %1, off offset:16"  : "=v"(S5) : "v"(xm1)); \
  asm volatile("global_load_dwordx4 %0, %1, off offset:128" : "=v"(S6) : "v"(xm1)); \
  asm volatile("global_load_dwordx4 %0, %1, off offset:144" : "=v"(S7) : "v"(xm1)); \
  asm volatile("global_load_dwordx4 %0, %1, off"            : "=v"(T0) : "v"(acp)); \
  asm volatile("global_load_dwordx4 %0, %1, off offset:16"  : "=v"(T1) : "v"(acp)); \
  asm volatile("global_load_dwordx4 %0, %1, off offset:128" : "=v"(T2) : "v"(acp)); \
  asm volatile("global_load_dwordx4 %0, %1, off offset:144" : "=v"(T3) : "v"(acp)); \
  xm0 += BK; xm1 += BK; acp += 128;                                            \
  asm volatile("" ::: "memory");

// 8 gl_lds into half K (uses current bptr = tile being prefetched)
#define GLDS(K)                                                                \
  _Pragma("unroll")                                                            \
  for (int b = 0; b < 8; ++b) {                                                \
    __builtin_amdgcn_global_load_lds(                                          \
        (__attribute__((address_space(1))) void*)(bptr + b * 65536 + (K) * 32),\
        (__attribute__((address_space(3))) void*)(&ldsw[(K) * 4096 + b * 512]),\
        16, 0, 0);                                                             \
  }                                                                            \
  asm volatile("" ::: "memory");

// transform S/T -> pk set (P00 m0k0, P10 m1k0, P01 m0k1, P11 m1k1)
#define TRANSFORM(P00, P10, P01, P11)                                          \
  {                                                                            \
    _Pragma("unroll")                                                          \
    for (int e = 0; e < 4; ++e) {                                              \
      const float a0 = bf2f(T0[e]),     a4 = bf2f(T0[e + 4]);                  \
      const float c0 = bf2f(T1[e]),     c4 = bf2f(T1[e + 4]);                  \
      const float b0 = bf2f(T2[e]),     b4 = bf2f(T2[e + 4]);                  \
      const float d0 = bf2f(T3[e]),     d4 = bf2f(T3[e + 4]);                  \
      P00[e]     = f2bf(fmaxf(S0[e] * a0 + c0, 0.f));                          \
      P00[e + 4] = f2bf(fmaxf(S1[e] * a4 + c4, 0.f));                          \
      P01[e]     = f2bf(fmaxf(S2[e] * b0 + d0, 0.f));                          \
      P01[e + 4] = f2bf(fmaxf(S3[e] * b4 + d4, 0.f));                          \
      P10[e]     = f2bf(fmaxf(S4[e] * a0 + c0, 0.f));                          \
      P10[e + 4] = f2bf(fmaxf(S5[e] * a4 + c4, 0.f));                          \
      P11[e]     = f2bf(fmaxf(S6[e] * b0 + d0, 0.f));                          \
      P11[e + 4] = f2bf(fmaxf(S7[e] * b4 + d4, 0.f));                          \
    }                                                                          \
  }

// read 8 B-frags from half K (asm, rule #18), then (optional) MFMA macro uses fr
#define DSREAD8(K, fr)                                                         \
  _Pragma("unroll")                                                            \
  for (int j = 0; j < 8; ++j) {                                                \
    asm volatile("ds_read_b128 %0, %1 offset:%2"                               \
                 : "=v"(fr[j]) : "v"(dsb), "i"((K) * 8192 + j * 1024));        \
  }                                                                            \
  asm volatile("s_waitcnt lgkmcnt(0)" ::: "memory");                           \
  SB;

#define MFMA16(PM0, PM1, fr)                                                   \
  __builtin_amdgcn_s_setprio(1);                                               \
  _Pragma("unroll")                                                            \
  for (int j = 0; j < 8; ++j) {                                                \
    accA[j] = __builtin_amdgcn_mfma_f32_16x16x32_bf16(                         \
        __builtin_bit_cast(bf16x8, PM0), fr[j], accA[j], 0, 0, 0);             \
    accB[j] = __builtin_amdgcn_mfma_f32_16x16x32_bf16(                         \
        __builtin_bit_cast(bf16x8, PM1), fr[j], accB[j], 0, 0, 0);             \
  }                                                                            \
  __builtin_amdgcn_s_setprio(0);

  // ---- prologue: A(0)+AC(0); B(0) both halves; transform pk(0); A(1) ----
  {
    ISSUE_AX();            // A(0): 12          out 12
    GLDS(0);               // B(0,k0): 8        out 20
    GLDS(1);               // B(0,k1): 8        out 28
    asm volatile("s_waitcnt vmcnt(16)" ::: "memory"); SB;   // A(0) home
    TRANSFORM(pA00, pA10, pA01, pA11);                      // pk(0)
    ISSUE_AX();            // A(1): 12          out 28
    asm volatile("s_waitcnt vmcnt(20)" ::: "memory"); SB;   // B(0,k0) home
  }

  // steady step t: entry out = {A(t+1):12, B(t,k1):8} = 20
#define STEP(PC00, PC10, PC01, PC11, PN00, PN10, PN01, PN11)                   \
  do {                                                                         \
    u16x8 fr[8];                                                               \
    bptr += BK;                              /* now points at tile t+1 */      \
    DSREAD8(0, fr);                          /* B(t,k0) frags */               \
    GLDS(0);                                 /* B(t+1,k0)  out 28 */           \
    MFMA16(PC00, PC10, fr);                  /* kk0 */                         \
    asm volatile("s_waitcnt vmcnt(8)" ::: "memory"); SB;  /* A(t+1)+B(t,k1) */ \
    TRANSFORM(PN00, PN10, PN01, PN11);       /* pk(t+1) */                     \
    DSREAD8(1, fr);                          /* B(t,k1) frags */               \
    ISSUE_AX();                              /* A(t+2): 12  out 20 */          \
    GLDS(1);                                 /* B(t+1,k1)  out 28 */           \
    MFMA16(PC01, PC11, fr);                  /* kk1 */                         \
    asm volatile("s_waitcnt vmcnt(20)" ::: "memory"); SB; /* B(t+1,k0) home */ \
  } while (0)

  // steps 0..61 (31 pairs; pk alternates A/B)
  for (int it = 0; it < 31; ++it) {
    STEP(pA00, pA10, pA01, pA11, pB00, pB10, pB01, pB11);
    STEP(pB00, pB10, pB01, pB11, pA00, pA10, pA01, pA11);
  }
  // step 62 (uses pkA=pk(62), writes pkB=pk(63); NO A-issue)
  {
    u16x8 fr[8];
    bptr += BK;                              // tile 63
    DSREAD8(0, fr);
    GLDS(0);                                 // B(63,k0)   out 28
    MFMA16(pA00, pA10, fr);
    asm volatile("s_waitcnt vmcnt(8)" ::: "memory"); SB;   // A(63)+B(62,k1)
    TRANSFORM(pB00, pB10, pB01, pB11);       // pk(63)
    DSREAD8(1, fr);
    GLDS(1);                                 // B(63,k1)   out 16
    MFMA16(pA01, pA11, fr);
    asm volatile("s_waitcnt vmcnt(8)" ::: "memory"); SB;   // B(63,k0) home
  }
  // step 63 (uses pkB; nothing prefetched)
  {
    u16x8 fr[8];
    DSREAD8(0, fr);
    MFMA16(pB00, pB10, fr);
    asm volatile("s_waitcnt vmcnt(0)" ::: "memory"); SB;   // B(63,k1) home
    DSREAD8(1, fr);
    MFMA16(pB01, pB11, fr);
  }

#undef STEP
#undef MFMA16
#undef DSREAD8
#undef TRANSFORM
#undef GLDS
#undef ISSUE_AX
#undef SB

  // epilogue: C/D layout col=lr, row=lc*4+rr ; accA rows +0, accB rows +16
#pragma unroll
  for (int j = 0; j < 8; ++j) {
    const int oc = wc * 128 + j * 16 + lr;
    const float bv = bias[oc];
    const size_t r0 = bm0 + wr * 32 + lc * 4;
#pragma unroll
    for (int rr = 0; rr < 4; ++rr) {
      out[(r0 + rr) * ODIM + oc]      = accA[j][rr] + bv;
      out[(r0 + 16 + rr) * ODIM + oc] = accB[j][rr] + bv;
    }
  }
}

extern "C" void kernel_launch(void* const* d_in, const int* in_sizes, int n_in,
                              void* d_out, int out_size, void* d_ws, size_t ws_size,
                              hipStream_t stream) {
  const float* x     = (const float*)d_in[0];
  const float* gamma = (const float*)d_in[1];
  const float* beta  = (const float*)d_in[2];
  const float* W     = (const float*)d_in[3];
  const float* b     = (const float*)d_in[4];
  float* out = (float*)d_out;

  // ws: psum[128][4096] | psq[128][4096] | AC bf16 [512*16] | Wb bf16 [256*4096]
  float* psum  = (float*)d_ws;
  float* psq   = psum + (size_t)CHUNKS * DDIM;
  unsigned short* AC = (unsigned short*)(psq + (size_t)CHUNKS * DDIM);
  unsigned short* Wb = AC + 512 * 16;

  k1_stats<<<dim3(4, CHUNKS), 256, 0, stream>>>(x, psum, psq);
  k2_finalize_wconv<<<64 + (ODIM * DDIM) / 1024, 256, 0, stream>>>(
      psum, psq, gamma, beta, W, AC, Wb);
  k3_bn_gemm<<<NROWS / BM, 256, 0, stream>>>(x, Wb, AC, b, out);
}

// Round 12
// 239.215 us; speedup vs baseline: 1.4925x; 1.4925x over previous
//
#include <hip/hip_runtime.h>
#include <hip/hip_bf16.h>

#define NROWS 32768
#define DDIM  4096
#define ODIM  256
#define EPSV  1e-5f

#define CHUNKS 128
#define RPC    256      // rows per chunk (CHUNKS*RPC == NROWS)

#define BM 128
#define BK 64
#define NKT (DDIM / BK)   // 64 K-steps

typedef __attribute__((ext_vector_type(4))) float          f32x4;
typedef __attribute__((ext_vector_type(8))) __bf16         bf16x8;
typedef __attribute__((ext_vector_type(8))) unsigned short u16x8;
typedef __attribute__((ext_vector_type(4))) unsigned short u16x4;

static __device__ __forceinline__ unsigned short f2bf(float f) {
  return __builtin_bit_cast(unsigned short, __float2bfloat16(f));
}

// ---------------- k1: per-chunk column partial sums (R1-proven) ----------------
__global__ __launch_bounds__(256) void k1_stats(const float* __restrict__ x,
                                                float* __restrict__ psum,
                                                float* __restrict__ psq) {
  const int col = blockIdx.x * 1024 + threadIdx.x * 4;
  const float* p = x + (size_t)blockIdx.y * RPC * DDIM + col;
  f32x4 s = {0.f, 0.f, 0.f, 0.f};
  f32x4 q = {0.f, 0.f, 0.f, 0.f};
#pragma unroll 8
  for (int r = 0; r < RPC; ++r) {
    f32x4 v = *(const f32x4*)p;
    p += DDIM;
    s += v;
    q += v * v;
  }
  *(f32x4*)(psum + (size_t)blockIdx.y * DDIM + col) = s;
  *(f32x4*)(psq  + (size_t)blockIdx.y * DDIM + col) = q;
}

// ---------------- k2a: finalize mean/var -> scale/shift ----------------
__global__ __launch_bounds__(256) void k2_stats_finalize(
    const float* __restrict__ psum, const float* __restrict__ psq,
    const float* __restrict__ gamma, const float* __restrict__ beta,
    float* __restrict__ scale, float* __restrict__ shift) {
  __shared__ float ss[4][64];
  __shared__ float sq[4][64];
  const int lane = threadIdx.x & 63;
  const int g    = threadIdx.x >> 6;          // 0..3
  const int d    = blockIdx.x * 64 + lane;
  float s = 0.f, qq = 0.f;
  for (int c = g * 32; c < (g + 1) * 32; ++c) {
    s  += psum[(size_t)c * DDIM + d];
    qq += psq [(size_t)c * DDIM + d];
  }
  ss[g][lane] = s;
  sq[g][lane] = qq;
  __syncthreads();
  if (g == 0) {
    s  = ss[0][lane] + ss[1][lane] + ss[2][lane] + ss[3][lane];
    qq = sq[0][lane] + sq[1][lane] + sq[2][lane] + sq[3][lane];
    const float inv = 1.0f / (float)NROWS;
    const float mean = s * inv;
    const float var  = fmaxf(qq * inv - mean * mean, 0.f);
    const float a = gamma[d] * rsqrtf(var + EPSV);
    scale[d] = a;
    shift[d] = beta[d] - mean * a;
  }
}

// ---------------- k2b: W fp32 -> bf16 ----------------
__global__ __launch_bounds__(256) void k2_wconv(const float* __restrict__ Wf,
                                                unsigned short* __restrict__ Wb) {
  const size_t i = ((size_t)blockIdx.x * 256 + threadIdx.x) * 4;
  f32x4 v = *(const f32x4*)(Wf + i);
  u16x4 o;
  o[0] = f2bf(v[0]); o[1] = f2bf(v[1]); o[2] = f2bf(v[2]); o[3] = f2bf(v[3]);
  *(u16x4*)(Wb + i) = o;
}

// ---------------- k3: fused normalize+relu+bf16 GEMM, counted-vmcnt pipeline ---
// 128x256 tile, BK=64, 512 thr (8 waves, 2x4 of 64x64). Double-buffered LDS.
// Per step t: asm-issue A(t+1) (4x dwordx4) -> gl_lds B(t+1) -> MFMA(t)
//  -> vmcnt(4) [A done, B still in flight] -> transform+ds_write A(t+1)
//  -> vmcnt(0)+lgkmcnt(0) -> raw s_barrier.
__global__ __launch_bounds__(512, 1) void k3_bn_gemm(
    const float* __restrict__ x,
    const unsigned short* __restrict__ Wb,
    const float* __restrict__ scale,
    const float* __restrict__ shift,
    const float* __restrict__ bias,
    float* __restrict__ out) {
  __shared__ unsigned short As[2][BM * BK];     // 2 x 16 KB, XOR-swizzled
  __shared__ unsigned short Bs[2][ODIM * BK];   // 2 x 32 KB, XOR-swizzled
  __shared__ float SF[DDIM];                    // 16 KB scale
  __shared__ float SH[DDIM];                    // 16 KB shift

  const int tid = threadIdx.x;
  const int l   = tid & 63;
  const int w   = tid >> 6;     // 0..7
  const int wr  = w >> 2;       // 0..1
  const int wc  = w & 3;        // 0..3
  const size_t bm0 = (size_t)blockIdx.x * BM;

  // --- scale/shift LDS preload ---
  ((f32x4*)SF)[tid * 2]     = ((const f32x4*)scale)[tid * 2];
  ((f32x4*)SF)[tid * 2 + 1] = ((const f32x4*)scale)[tid * 2 + 1];
  ((f32x4*)SH)[tid * 2]     = ((const f32x4*)shift)[tid * 2];
  ((f32x4*)SH)[tid * 2 + 1] = ((const f32x4*)shift)[tid * 2 + 1];

  // --- A staging geometry: thread covers rows rA, rA+64; 8-col unit uA ---
  const int rA = tid >> 3;      // 0..63
  const int uA = tid & 7;       // 0..7
  const float* xp0 = x + (bm0 + rA) * (size_t)DDIM + uA * 8;
  const float* xp1 = xp0 + (size_t)64 * DDIM;
  const int awo = rA * 64 + ((uA ^ (rA & 7)) << 3);   // ushort offset in buf
  int ktb = uA * 8;                                   // scale/shift col base

  // --- B staging: gl_lds, linear LDS dest + inverse-swizzled global src ---
  const unsigned short* bsrc[4];
#pragma unroll
  for (int q = 0; q < 4; ++q) {
    const int p  = w * 256 + q * 64 + l;   // 16B-unit index into a B buffer
    const int o  = p >> 3;
    const int up = p & 7;
    bsrc[q] = Wb + (size_t)o * DDIM + ((up ^ (o & 7)) << 3);
  }

  // --- fragment LDS offsets (ushort units, within one buffer); kk -> ^32 ---
  int offA[4], offB[4];
#pragma unroll
  for (int i = 0; i < 4; ++i) {
    const int row = wr * 64 + i * 16 + (l & 15);
    offA[i] = row * 64 + (((l >> 4) ^ (row & 7)) << 3);
  }
#pragma unroll
  for (int j = 0; j < 4; ++j) {
    const int row = wc * 64 + j * 16 + (l & 15);
    offB[j] = row * 64 + (((l >> 4) ^ (row & 7)) << 3);
  }

  const f32x4 zero = {0.f, 0.f, 0.f, 0.f};
  f32x4 acc[4][4];
#pragma unroll
  for (int i = 0; i < 4; ++i)
#pragma unroll
    for (int j = 0; j < 4; ++j) acc[i][j] = zero;

#define ISSUE_A(V00, V01, V10, V11)                                            \
  asm volatile("global_load_dwordx4 %0, %1, off" : "=v"(V00) : "v"(xp0));      \
  asm volatile("global_load_dwordx4 %0, %1, off" : "=v"(V01) : "v"(xp0 + 4));  \
  asm volatile("global_load_dwordx4 %0, %1, off" : "=v"(V10) : "v"(xp1));      \
  asm volatile("global_load_dwordx4 %0, %1, off" : "=v"(V11) : "v"(xp1 + 4));  \
  asm volatile("" ::: "memory");

#define ISSUE_B(BUFI)                                                          \
  _Pragma("unroll")                                                            \
  for (int q = 0; q < 4; ++q) {                                                \
    __builtin_amdgcn_global_load_lds(                                          \
        (__attribute__((address_space(1))) void*)bsrc[q],                      \
        (__attribute__((address_space(3))) void*)(                             \
            &Bs[BUFI][(w * 256 + q * 64) * 8]),                                \
        16, 0, 0);                                                             \
    bsrc[q] += BK;                                                             \
  }

#define TRANSFORM_WRITE(BUFI, V00, V01, V10, V11)                              \
  {                                                                            \
    f32x4 sa0 = *(const f32x4*)&SF[ktb];                                       \
    f32x4 sa1 = *(const f32x4*)&SF[ktb + 4];                                   \
    f32x4 sc0 = *(const f32x4*)&SH[ktb];                                       \
    f32x4 sc1 = *(const f32x4*)&SH[ktb + 4];                                   \
    ktb += BK;                                                                 \
    u16x8 pk0, pk1;                                                            \
    _Pragma("unroll")                                                          \
    for (int e = 0; e < 4; ++e) {                                              \
      pk0[e]     = f2bf(fmaxf(V00[e] * sa0[e] + sc0[e], 0.f));                 \
      pk0[e + 4] = f2bf(fmaxf(V01[e] * sa1[e] + sc1[e], 0.f));                 \
      pk1[e]     = f2bf(fmaxf(V10[e] * sa0[e] + sc0[e], 0.f));                 \
      pk1[e + 4] = f2bf(fmaxf(V11[e] * sa1[e] + sc1[e], 0.f));                 \
    }                                                                          \
    *(u16x8*)&As[BUFI][awo]        = pk0;                                      \
    *(u16x8*)&As[BUFI][awo + 4096] = pk1;                                      \
  }

#define MFMA_PHASE(BUFI)                                                       \
  _Pragma("unroll")                                                            \
  for (int kk = 0; kk < 2; ++kk) {                                             \
    const int kx = kk << 5;                                                    \
    bf16x8 af[4], bfr[4];                                                      \
    _Pragma("unroll")                                                          \
    for (int i = 0; i < 4; ++i)                                                \
      af[i] = __builtin_bit_cast(bf16x8,                                       \
                                 *(const u16x8*)&As[BUFI][offA[i] ^ kx]);      \
    _Pragma("unroll")                                                          \
    for (int j = 0; j < 4; ++j)                                                \
      bfr[j] = __builtin_bit_cast(bf16x8,                                      \
                                  *(const u16x8*)&Bs[BUFI][offB[j] ^ kx]);     \
    _Pragma("unroll")                                                          \
    for (int i = 0; i < 4; ++i)                                                \
      _Pragma("unroll")                                                        \
      for (int j = 0; j < 4; ++j)                                              \
        acc[i][j] = __builtin_amdgcn_mfma_f32_16x16x32_bf16(                   \
            af[i], bfr[j], acc[i][j], 0, 0, 0);                                \
  }

  // ---- prologue: stage tile 0 into buffers [0] ----
  {
    f32x4 v00, v01, v10, v11;
    ISSUE_A(v00, v01, v10, v11);
    ISSUE_B(0);
    xp0 += BK; xp1 += BK;
    // scale/shift LDS stores visible before any thread reads them
    asm volatile("s_waitcnt lgkmcnt(0)" ::: "memory");
    __builtin_amdgcn_sched_barrier(0);
    __builtin_amdgcn_s_barrier();
    asm volatile("s_waitcnt vmcnt(4)" ::: "memory");   // A0 done, B0 in flight
    __builtin_amdgcn_sched_barrier(0);
    TRANSFORM_WRITE(0, v00, v01, v10, v11);
    asm volatile("s_waitcnt vmcnt(0) lgkmcnt(0)" ::: "memory");
    __builtin_amdgcn_sched_barrier(0);
    __builtin_amdgcn_s_barrier();
  }

#define STEP(CUR, PF)                                                          \
  do {                                                                         \
    f32x4 v00, v01, v10, v11;                                                  \
    if (PF) {                                                                  \
      ISSUE_A(v00, v01, v10, v11);                                             \
      ISSUE_B((CUR) ^ 1);                                                      \
      xp0 += BK; xp1 += BK;                                                    \
    }                                                                          \
    MFMA_PHASE(CUR);                                                           \
    if (PF) {                                                                  \
      asm volatile("s_waitcnt vmcnt(4)" ::: "memory");                         \
      __builtin_amdgcn_sched_barrier(0);                                       \
      TRANSFORM_WRITE((CUR) ^ 1, v00, v01, v10, v11);                          \
    }                                                                          \
    asm volatile("s_waitcnt vmcnt(0) lgkmcnt(0)" ::: "memory");                \
    __builtin_amdgcn_sched_barrier(0);                                         \
    __builtin_amdgcn_s_barrier();                                              \
  } while (0)

  // steps 0..61
  for (int kt = 0; kt < NKT - 2; kt += 2) {
    STEP(0, true);
    STEP(1, true);
  }
  STEP(0, true);    // step 62, prefetch tile 63 into buf 1
  STEP(1, false);   // step 63
#undef STEP
#undef MFMA_PHASE
#undef TRANSFORM_WRITE
#undef ISSUE_B
#undef ISSUE_A

  // epilogue: C/D layout col=l&15, row=(l>>4)*4+rr
  const int cl = l & 15;
  const int rg = l >> 4;
#pragma unroll
  for (int j = 0; j < 4; ++j) {
    const int oc = wc * 64 + j * 16 + cl;
    const float bv = bias[oc];
#pragma unroll
    for (int i = 0; i < 4; ++i) {
      const size_t r0 = bm0 + wr * 64 + i * 16 + rg * 4;
#pragma unroll
      for (int rr = 0; rr < 4; ++rr) {
        out[(r0 + rr) * ODIM + oc] = acc[i][j][rr] + bv;
      }
    }
  }
}

extern "C" void kernel_launch(void* const* d_in, const int* in_sizes, int n_in,
                              void* d_out, int out_size, void* d_ws, size_t ws_size,
                              hipStream_t stream) {
  const float* x     = (const float*)d_in[0];
  const float* gamma = (const float*)d_in[1];
  const float* beta  = (const float*)d_in[2];
  const float* W     = (const float*)d_in[3];
  const float* b     = (const float*)d_in[4];
  float* out = (float*)d_out;

  float* psum  = (float*)d_ws;
  float* psq   = psum + (size_t)CHUNKS * DDIM;
  float* scale = psum + 2 * (size_t)CHUNKS * DDIM;
  float* shift = scale + DDIM;
  unsigned short* Wb = (unsigned short*)(shift + DDIM);

  k1_stats<<<dim3(4, CHUNKS), 256, 0, stream>>>(x, psum, psq);
  k2_stats_finalize<<<DDIM / 64, 256, 0, stream>>>(psum, psq, gamma, beta, scale, shift);
  k2_wconv<<<(ODIM * DDIM) / 1024, 256, 0, stream>>>(W, Wb);
  k3_bn_gemm<<<NROWS / BM, 512, 0, stream>>>(x, Wb, scale, shift, b, out);
}